// Round 11
// baseline (3336.276 us; speedup 1.0000x reference)
//
#include <hip/hip_runtime.h>
#include <stdint.h>

// ---------------- types / helpers ----------------
typedef __attribute__((ext_vector_type(8))) short bf16x8;
typedef __attribute__((ext_vector_type(4))) float f32x4;

__device__ __forceinline__ float bf2f(unsigned short u) {
  unsigned int x = ((unsigned int)u) << 16;
  return __builtin_bit_cast(float, x);
}
__device__ __forceinline__ unsigned short f2bf(float f) {
  unsigned int x = __builtin_bit_cast(unsigned int, f);
  unsigned int r = x + 0x7FFFu + ((x >> 16) & 1u);
  return (unsigned short)(r >> 16);
}
__device__ __forceinline__ float silu(float v) { return v / (1.f + __expf(-v)); }
__device__ __forceinline__ f32x4 fz4() { f32x4 z; z[0]=0.f; z[1]=0.f; z[2]=0.f; z[3]=0.f; return z; }

#define LSEQ 4096
#define DMODEL 256
#define NIN 1284
#define NINP 1408   // padded to 11*128

// ---------------- prep: weight cast/pad/interleave + x transpose + smean zero ----------------
__global__ __launch_bounds__(256) void k_prep(const float* __restrict__ w_in,
                                              const float* __restrict__ w_out,
                                              unsigned short* __restrict__ wpad,
                                              unsigned short* __restrict__ woutbf,
                                              const float* __restrict__ x,
                                              unsigned short* __restrict__ ubf,
                                              float* __restrict__ smean) {
  int bid = blockIdx.x;
  int tid = threadIdx.x;
  if (bid < 1920) {
    if (bid < 8) smean[bid * 256 + tid] = 0.f;   // zero SE accumulator (gemm2 atomics)
    int idx = bid * 256 + tid;
    const int tot1 = NINP * DMODEL;           // 360448
    if (idx < tot1) {
      int n = idx / DMODEL, k = idx % DMODEL;
      int src = (n < 512) ? ((n & 1) ? 256 + (n >> 1) : (n >> 1)) : n;
      float v = (src < NIN) ? w_in[src * DMODEL + k] : 0.f;
      wpad[idx] = f2bf(v);
    } else {
      int j = idx - tot1;                      // 256*512 = 131072
      woutbf[j] = f2bf(w_out[j]);
    }
    return;
  }
  __shared__ float t[64][65];
  int r = (bid - 1920) & 255;
  int b = (bid - 1920) >> 8;
  int lt = r >> 2, kt = r & 3;
  int l0 = lt * 64, k0 = kt * 64;
  int j = tid & 63, i0 = tid >> 6;
  for (int rr = 0; rr < 16; rr++) {
    int ki = i0 + rr * 4;
    t[ki][j] = x[(size_t)(b * DMODEL + k0 + ki) * LSEQ + l0 + j];
  }
  __syncthreads();
  for (int rr = 0; rr < 16; rr++) {
    int li = i0 + rr * 4;
    ubf[(size_t)(b * LSEQ + l0 + li) * DMODEL + k0 + j] = f2bf(t[j][li]);
  }
}

// ---------------- bf16 MFMA GEMM, 128x128 tile, BK=64, T2-swizzled LDS ----------------
// dt tile (EPI==2, n0>=1280): only 4 live cols -> stage B rows 0..15 only, 4 MFMA/step.
// EPI=0 (fallback): combined zx[m][1280] (z0/x0 interleaved in cols 0..511) + dt
// EPI=1: res_t bf16 [b][c][l] via outBF; dtb = smean (fused SE column sums, atomic)
// EPI=2 (chunked): zc=silu(z0)*x0 -> zcat cols 0..255; z -> zbuf; xBC -> xbc; dt -> dtb
template <int KDIM, int LDA, int LDB, int EPI>
__global__ __launch_bounds__(256) void k_gemm(const unsigned short* __restrict__ A,
                                              const unsigned short* __restrict__ B,
                                              float* __restrict__ outF,
                                              unsigned short* __restrict__ outBF,
                                              unsigned short* __restrict__ outBF2,
                                              float* __restrict__ dtb, int tilesN) {
  __shared__ __align__(16) short lds[17408];     // 34816 B
  short* As = lds;
  short* Bs = lds + 8192;
  int nwg = gridDim.x;
  int orig = blockIdx.x;
  int wgid = (nwg & 7) ? orig : ((orig & 7) * (nwg >> 3) + (orig >> 3));
  int tn = wgid % tilesN, tm = wgid / tilesN;
  int m0 = tm * 128, n0 = tn * 128;
  int tid = threadIdx.x;
  int w = tid >> 6, lane = tid & 63;
  int wr = w >> 1, wc = w & 1;
  bool thin = (EPI != 1) && (n0 >= 1280);        // dt tile: only cols 0..3 live
  f32x4 acc[4][4];
  for (int i = 0; i < 4; i++)
    for (int j = 0; j < 4; j++) acc[i][j] = fz4();

  for (int kt = 0; kt < KDIM / 64; kt++) {
    int k0 = kt * 64;
    for (int i = 0; i < 4; i++) {
      int rowblk = w * 32 + i * 8;
      int row = rowblk + (lane >> 3);
      int kc = ((lane & 7) ^ (row & 7)) * 8;   // pre-swizzled source granule
      const unsigned short* ga = A + (size_t)(m0 + row) * LDA + k0 + kc;
      __builtin_amdgcn_global_load_lds((const __attribute__((address_space(1))) unsigned int*)ga,
                                       (__attribute__((address_space(3))) unsigned int*)&As[rowblk * 64],
                                       16, 0, 0);
      if (!thin || rowblk < 16) {
        const unsigned short* gb = B + (size_t)(n0 + row) * LDB + k0 + kc;
        __builtin_amdgcn_global_load_lds((const __attribute__((address_space(1))) unsigned int*)gb,
                                         (__attribute__((address_space(3))) unsigned int*)&Bs[rowblk * 64],
                                         16, 0, 0);
      }
    }
    __syncthreads();
    int nlim = thin ? 1 : 4;
    for (int kk = 0; kk < 64; kk += 32) {
      int gq = (kk >> 3) + (lane >> 4);       // logical granule 0..7
      bf16x8 af[4], bfr[4];
      for (int mi = 0; mi < 4; mi++) {
        int rt = wr * 64 + mi * 16 + (lane & 15);
        af[mi] = *(const bf16x8*)((const char*)As + rt * 128 + ((gq ^ (rt & 7)) << 4));
      }
      for (int ni = 0; ni < nlim; ni++) {
        int rs = wc * 64 + ni * 16 + (lane & 15);
        bfr[ni] = *(const bf16x8*)((const char*)Bs + rs * 128 + ((gq ^ (rs & 7)) << 4));
      }
      for (int mi = 0; mi < 4; mi++)
        for (int ni = 0; ni < nlim; ni++)
          acc[mi][ni] = __builtin_amdgcn_mfma_f32_16x16x32_bf16(af[mi], bfr[ni], acc[mi][ni], 0, 0, 0);
    }
    __syncthreads();
  }

  int fq = lane >> 4, fr = lane & 15;
  if constexpr (EPI == 1) {
    // res_t bf16 [b][c][l]: stage transposed (c-major, stride 136), coalesced row stores
    short* Ctl = lds;
    for (int mi = 0; mi < 4; mi++)
      for (int ni = 0; ni < 4; ni++)
        for (int j = 0; j < 4; j++) {
          int r = wr * 64 + mi * 16 + fq * 4 + j;     // l within tile
          int cch = wc * 64 + ni * 16 + fr;           // c within tile
          Ctl[cch * 136 + r] = (short)f2bf(acc[mi][ni][j]);
        }
    __syncthreads();
    int b = m0 >> 12, l0 = m0 & 4095;
    for (int it = 0; it < 4; it++) {
      int row = it * 32 + (tid >> 3);
      int cc = (tid & 7) * 16;
      uint4 v0 = *(const uint4*)&Ctl[row * 136 + cc];
      uint4 v1 = *(const uint4*)&Ctl[row * 136 + cc + 8];
      unsigned short* dst = outBF + ((size_t)(b * 256 + n0 + row)) * 4096 + l0 + cc;
      *(uint4*)dst = v0;
      *(uint4*)&dst[8] = v1;
    }
    // fused SE-mean column partials: dtb == smean
    {
      int cch = tid >> 1, hf = tid & 1;
      const short* prow = &Ctl[cch * 136 + hf * 64];
      float s = 0.f;
      for (int q = 0; q < 8; q++) {
        uint4 v = *(const uint4*)&prow[q * 8];
        const unsigned short* pv = (const unsigned short*)&v;
#pragma unroll
        for (int e = 0; e < 8; e++) s += bf2f(pv[e]);
      }
      s += __shfl_xor(s, 1, 64);
      if (!hf) atomicAdd(&dtb[b * 256 + n0 + cch], s);
    }
  } else if constexpr (EPI == 2) {
    unsigned short* xbc = (unsigned short*)outF;
    if (n0 >= 1280) {
      if (wc == 0 && fr < 4) {
        for (int mi = 0; mi < 4; mi++)
          for (int j = 0; j < 4; j++) {
            int m = m0 + wr * 64 + mi * 16 + fq * 4 + j;
            dtb[m * 4 + fr] = acc[mi][0][j];
          }
      }
    } else if (n0 < 512) {
      // zc = silu(z0)*x0 : even fr holds z0, odd fr holds x0 (interleaved rows)
      short* Ct = lds;
      for (int mi = 0; mi < 4; mi++)
        for (int ni = 0; ni < 4; ni++)
          for (int j = 0; j < 4; j++) {
            float v = acc[mi][ni][j];
            float vp = __shfl_xor(v, 1, 64);
            if (!(fr & 1)) {
              float zc = silu(v) * vp;
              Ct[(wr * 64 + mi * 16 + fq * 4 + j) * 72 + wc * 32 + ni * 8 + (fr >> 1)] =
                  (short)f2bf(zc);
            }
          }
      __syncthreads();
      int r = tid >> 1, base = (tid & 1) * 32;
      for (int it = 0; it < 4; it++) {
        int cc = base + it * 8;
        uint4 v = *(const uint4*)&Ct[r * 72 + cc];
        *(uint4*)&outBF[(size_t)(m0 + r) * 512 + (n0 >> 1) + cc] = v;
      }
    } else {
      short* Ct = lds;
      for (int mi = 0; mi < 4; mi++)
        for (int ni = 0; ni < 4; ni++)
          for (int j = 0; j < 4; j++)
            Ct[(wr * 64 + mi * 16 + fq * 4 + j) * 136 + wc * 64 + ni * 16 + fr] =
                (short)f2bf(acc[mi][ni][j]);
      __syncthreads();
      int rr = tid >> 4, cc = (tid & 15) * 8;
      for (int it = 0; it < 8; it++) {
        int r = it * 16 + rr;
        uint4 v = *(const uint4*)&Ct[r * 136 + cc];
        if (n0 < 768) *(uint4*)&outBF2[(size_t)(m0 + r) * 256 + (n0 - 512) + cc] = v;
        else *(uint4*)&xbc[(size_t)(m0 + r) * 512 + (n0 - 768) + cc] = v;
      }
    }
  } else {  // EPI == 0 fallback
    bool dttile = (n0 >= 1280);
    if (dttile) {
      if (wc == 0 && fr < 4) {
        for (int mi = 0; mi < 4; mi++)
          for (int j = 0; j < 4; j++) {
            int m = m0 + wr * 64 + mi * 16 + fq * 4 + j;
            dtb[m * 4 + fr] = acc[mi][0][j];
          }
      }
    } else {
      short* Ct = lds;
      for (int mi = 0; mi < 4; mi++)
        for (int ni = 0; ni < 4; ni++)
          for (int j = 0; j < 4; j++)
            Ct[(wr * 64 + mi * 16 + fq * 4 + j) * 136 + wc * 64 + ni * 16 + fr] =
                (short)f2bf(acc[mi][ni][j]);
      __syncthreads();
      int rr = tid >> 4, cc = (tid & 15) * 8;
      for (int it = 0; it < 8; it++) {
        int r = it * 16 + rr;
        uint4 v = *(const uint4*)&Ct[r * 136 + cc];
        *(uint4*)&outBF[(size_t)(m0 + r) * 1280 + n0 + cc] = v;
      }
    }
  }
}

// ---------------- depthwise causal conv (4 taps) + SiLU; + dtpre tail blocks ----------------
__global__ __launch_bounds__(256) void k_conv(const unsigned short* __restrict__ src, int stride,
                                              const float* __restrict__ conv_w,
                                              const float* __restrict__ conv_b,
                                              unsigned short* __restrict__ xs,
                                              unsigned short* __restrict__ bc,
                                              unsigned short* __restrict__ xsT,
                                              unsigned short* __restrict__ bT,
                                              const float* __restrict__ dtraw,
                                              const float* __restrict__ dt_bias,
                                              const float* __restrict__ A_log,
                                              float* __restrict__ dts,
                                              float* __restrict__ cums) {
  __shared__ __align__(16) unsigned short xt[35 * 512];
  int bid = blockIdx.x;
  int tid = threadIdx.x;
  if (bid >= 1024) {
    int w4 = tid >> 6, lane = tid & 63;
    int gc = (bid - 1024) * 4 + w4;
    int bh = gc >> 6, cc = gc & 63;
    int b2 = bh >> 2, h2 = bh & 3;
    int t = cc * 64 + lane;
    float v = dtraw[(size_t)(b2 * LSEQ + t) * 4 + h2] + dt_bias[h2];
    float dt = (v > 20.f) ? v : log1pf(__expf(v));
    float Ah = -__expf(A_log[h2]);
    float s = dt * Ah;
    for (int off = 1; off < 64; off <<= 1) {
      float o = __shfl_up(s, off, 64);
      if (lane >= off) s += o;
    }
    dts[bh * LSEQ + t] = dt;
    cums[bh * LSEQ + t] = s;
    return;
  }
  int b = bid >> 7;
  int t0 = (bid & 127) * 32;
  for (int id = tid; id < 35 * 64; id += 256) {
    int r = id >> 6, ch = id & 63;
    int t = t0 - 3 + r;
    float4 v;
    if (t < 0) v = make_float4(0.f, 0.f, 0.f, 0.f);
    else v = *(const float4*)&src[(size_t)(b * LSEQ + t) * stride + ch * 8];
    *(float4*)&xt[r * 512 + ch * 8] = v;
  }
  __syncthreads();
  int c0 = tid, c1 = tid + 256;
  float w0[4], w1[4];
  for (int k = 0; k < 4; k++) { w0[k] = conv_w[c0 * 4 + k]; w1[k] = conv_w[c1 * 4 + k]; }
  float bb0 = conv_b[c0], bb1 = conv_b[c1];
  unsigned short xa0[32], xa1[32];
#pragma unroll
  for (int tl = 0; tl < 32; tl++) {
    float a0 = bb0, a1 = bb1;
    for (int k = 0; k < 4; k++) {
      a0 += bf2f(xt[(tl + k) * 512 + c0]) * w0[k];
      a1 += bf2f(xt[(tl + k) * 512 + c1]) * w1[k];
    }
    a0 = silu(a0); a1 = silu(a1);
    unsigned short u0 = f2bf(a0), u1 = f2bf(a1);
    xa0[tl] = u0; xa1[tl] = u1;
    size_t row = (size_t)(b * LSEQ + t0 + tl);
    xs[row * 256 + c0] = u0;
    bc[row * 256 + (c1 - 256)] = u1;
  }
  if (xsT) {
    const uint4* p0 = (const uint4*)xa0;
    for (int k = 0; k < 4; k++)
      *(uint4*)&xsT[((size_t)(b * 256 + c0)) * LSEQ + t0 + k * 8] = p0[k];
    if (c1 < 384) {
      const uint4* p1 = (const uint4*)xa1;
      for (int k = 0; k < 4; k++)
        *(uint4*)&bT[((size_t)(b * 128 + (c1 - 256))) * LSEQ + t0 + k * 8] = p1[k];
    }
  }
}

// ---------------- OLD sequential scan (ws fallback) ----------------
__global__ __launch_bounds__(256) void k_scan(const unsigned short* __restrict__ xs,
                                              const unsigned short* __restrict__ bc,
                                              const float* __restrict__ dtb,
                                              const float* __restrict__ dt_bias,
                                              const float* __restrict__ A_log,
                                              const float* __restrict__ Dp,
                                              unsigned short* __restrict__ y) {
  __shared__ __align__(16) unsigned short bcl[32 * 256];
  __shared__ float xsl[32][4];
  __shared__ float dtl[32], dal[32];
  int bid = blockIdx.x;
  int b = bid >> 6;
  int h = (bid >> 4) & 3;
  int pg = bid & 15;
  int tid = threadIdx.x, w = tid >> 6, lane = tid & 63;
  int p = pg * 4 + w;
  float Ah = -expf(A_log[h]);
  float Dh = Dp[h];
  float bias = dt_bias[h];
  float h0 = 0.f, h1 = 0.f;
  for (int t0 = 0; t0 < LSEQ; t0 += 32) {
    for (int id = tid; id < 32 * 32; id += 256) {
      int r = id >> 5, ch = id & 31;
      *(float4*)&bcl[r * 256 + ch * 8] =
          *(const float4*)&bc[(size_t)(b * LSEQ + t0 + r) * 256 + ch * 8];
    }
    if (tid < 128) {
      int r = tid >> 2, pp = tid & 3;
      xsl[r][pp] = bf2f(xs[(size_t)(b * LSEQ + t0 + r) * 256 + h * 64 + pg * 4 + pp]);
    } else if (tid < 160) {
      int r = tid - 128;
      float v = dtb[(size_t)(b * LSEQ + t0 + r) * 4 + h] + bias;
      float dt = (v > 20.f) ? v : log1pf(expf(v));
      dtl[r] = dt;
      dal[r] = expf(dt * Ah);
    }
    __syncthreads();
    for (int tl = 0; tl < 32; tl++) {
      float dtv = dtl[tl], dav = dal[tl], xv = xsl[tl][w];
      float bn  = bf2f(bcl[tl * 256 + lane]);
      float bn2 = bf2f(bcl[tl * 256 + 64 + lane]);
      float cn  = bf2f(bcl[tl * 256 + 128 + lane]);
      float cn2 = bf2f(bcl[tl * 256 + 192 + lane]);
      float coef = dtv * xv;
      h0 = h0 * dav + coef * bn;
      h1 = h1 * dav + coef * bn2;
      float part = h0 * cn + h1 * cn2;
      for (int off = 32; off; off >>= 1) part += __shfl_xor(part, off, 64);
      if (lane == 0)
        y[(size_t)(b * LSEQ + t0 + tl) * 256 + h * 64 + p] = f2bf(part + Dh * xv);
    }
    __syncthreads();
  }
}

// ---------------- chunk phase A ----------------
__global__ __launch_bounds__(256) void k_chunkA(const unsigned short* __restrict__ bc,
                                                const unsigned short* __restrict__ xsT,
                                                const unsigned short* __restrict__ bT,
                                                const float* __restrict__ dts,
                                                const float* __restrict__ cums,
                                                unsigned short* __restrict__ ST,
                                                unsigned short* __restrict__ yb) {
  __shared__ __align__(16) unsigned short sh[25088];
  unsigned short* Bsm = sh;
  unsigned short* BTs = sh + 8192;
  unsigned short* XT  = sh + 16384;
  unsigned short* Ms  = sh + 20480;
  __shared__ float dtl[64], cuml[64], scl[64];
  int bid = blockIdx.x;
  int bh = bid >> 6, c = bid & 63;
  int b = bh >> 2, h = bh & 3;
  int m0 = b * LSEQ + c * 64;
  int tid = threadIdx.x, w = tid >> 6, lane = tid & 63;

  if (tid < 64) {
    dtl[tid] = dts[bh * LSEQ + c * 64 + tid];
    cuml[tid] = cums[bh * LSEQ + c * 64 + tid];
  }
  __syncthreads();
  float cumQ = cuml[63];

  for (int it = 0; it < 4; it++) {
    int idx = it * 256 + tid, row = idx >> 4, g = idx & 15;
    uint4 v = *(const uint4*)&bc[(size_t)(m0 + row) * 256 + g * 8];
    *(uint4*)((char*)Bsm + row * 256 + ((g ^ (row & 7)) << 4)) = v;
  }
  for (int it = 0; it < 2; it++) {
    int idx = it * 256 + tid, row = idx >> 3, g = idx & 7;
    uint4 v = *(const uint4*)&xsT[((size_t)(b * 256 + h * 64 + row)) * LSEQ + c * 64 + g * 8];
    *(uint4*)((char*)XT + row * 128 + ((g ^ (row & 7)) << 4)) = v;
  }
  if (tid < 64) scl[tid] = dtl[tid] * __expf(cumQ - cuml[tid]);
  __syncthreads();
  for (int it = 0; it < 4; it++) {
    int idx = it * 256 + tid, row = idx >> 3, g = idx & 7;
    uint4 v = *(const uint4*)&bT[((size_t)(b * 128 + row)) * LSEQ + c * 64 + g * 8];
    const unsigned short* pv = (const unsigned short*)&v;
    uint4 o; unsigned short* po = (unsigned short*)&o;
#pragma unroll
    for (int e = 0; e < 8; e++) po[e] = f2bf(bf2f(pv[e]) * scl[g * 8 + e]);
    *(uint4*)((char*)BTs + row * 128 + ((g ^ (row & 7)) << 4)) = o;
  }

  int rt = w * 16 + (lane & 15);
  const unsigned short* arow = bc + (size_t)(m0 + rt) * 256 + 128;
  f32x4 acc1[4];
#pragma unroll
  for (int i = 0; i < 4; i++) acc1[i] = fz4();
#pragma unroll
  for (int ks = 0; ks < 4; ks++) {
    int g = ks * 4 + (lane >> 4);
    bf16x8 a = *(const bf16x8*)&arow[g * 8];
#pragma unroll
    for (int ni = 0; ni < 4; ni++) {
      int rs = ni * 16 + (lane & 15);
      bf16x8 bfr = *(const bf16x8*)((char*)Bsm + rs * 256 + ((g ^ (rs & 7)) << 4));
      acc1[ni] = __builtin_amdgcn_mfma_f32_16x16x32_bf16(a, bfr, acc1[ni], 0, 0, 0);
    }
  }
#pragma unroll
  for (int ni = 0; ni < 4; ni++)
#pragma unroll
    for (int j = 0; j < 4; j++) {
      int t = w * 16 + (lane >> 4) * 4 + j;
      int s = ni * 16 + (lane & 15);
      float v = 0.f;
      if (t >= s) v = acc1[ni][j] * __expf(cuml[t] - cuml[s]) * dtl[s];
      *(unsigned short*)((char*)Ms + t * 128 + (((s >> 3) ^ (t & 7)) << 4) + ((s & 7) << 1)) = f2bf(v);
    }
  __syncthreads();

  f32x4 acc2[4], acc3[8];
#pragma unroll
  for (int i = 0; i < 4; i++) acc2[i] = fz4();
#pragma unroll
  for (int i = 0; i < 8; i++) acc3[i] = fz4();
#pragma unroll
  for (int ks = 0; ks < 2; ks++) {
    int g = ks * 4 + (lane >> 4);
    bf16x8 xf[4];
#pragma unroll
    for (int ni = 0; ni < 4; ni++) {
      int rp = ni * 16 + (lane & 15);
      xf[ni] = *(const bf16x8*)((char*)XT + rp * 128 + ((g ^ (rp & 7)) << 4));
    }
    {
      bf16x8 a = *(const bf16x8*)((char*)Ms + rt * 128 + ((g ^ (rt & 7)) << 4));
#pragma unroll
      for (int ni = 0; ni < 4; ni++)
        acc2[ni] = __builtin_amdgcn_mfma_f32_16x16x32_bf16(a, xf[ni], acc2[ni], 0, 0, 0);
    }
    {
      bf16x8 a3 = xf[w];
#pragma unroll
      for (int ni = 0; ni < 8; ni++) {
        int rn = ni * 16 + (lane & 15);
        bf16x8 bfr = *(const bf16x8*)((char*)BTs + rn * 128 + ((g ^ (rn & 7)) << 4));
        acc3[ni] = __builtin_amdgcn_mfma_f32_16x16x32_bf16(a3, bfr, acc3[ni], 0, 0, 0);
      }
    }
  }
  __syncthreads();
  unsigned short* STst = sh;
#pragma unroll
  for (int ni = 0; ni < 4; ni++)
#pragma unroll
    for (int j = 0; j < 4; j++) {
      int t = w * 16 + (lane >> 4) * 4 + j;
      int p = ni * 16 + (lane & 15);
      Ms[t * 72 + p] = f2bf(acc2[ni][j]);
    }
#pragma unroll
  for (int ni = 0; ni < 8; ni++)
#pragma unroll
    for (int j = 0; j < 4; j++) {
      int p = w * 16 + (lane >> 4) * 4 + j;
      int n = ni * 16 + (lane & 15);
      STst[p * 136 + n] = f2bf(acc3[ni][j]);
    }
  __syncthreads();
  {
    int rr = tid >> 3, cc = (tid & 7) * 8;
    for (int it = 0; it < 2; it++) {
      int t = it * 32 + rr;
      uint4 v = *(const uint4*)&Ms[t * 72 + cc];
      *(uint4*)&yb[(size_t)(m0 + t) * 256 + h * 64 + cc] = v;
    }
  }
  {
    unsigned short* stp = ST + ((size_t)bid << 13);
    int rr = tid >> 2, cc = (tid & 3) * 32;
    for (int q = 0; q < 4; q++) {
      uint4 v = *(const uint4*)&STst[rr * 136 + cc + q * 8];
      *(uint4*)&stp[rr * 128 + cc + q * 8] = v;
    }
  }
}

// ---------------- chunk phase B: sequential state carry (ST bf16) ----------------
__global__ __launch_bounds__(256) void k_chunkB(const unsigned short* __restrict__ ST,
                                                const float* __restrict__ cums,
                                                unsigned short* __restrict__ HT) {
  int bid = blockIdx.x;
  int bh = bid >> 3, psl = bid & 7;
  int p = psl * 8 + (threadIdx.x >> 5);
  int n0 = (threadIdx.x & 31) * 4;
  float H[4] = {0.f, 0.f, 0.f, 0.f};
  for (int c = 0; c < 64; c++) {
    size_t base = (size_t)(bh * 64 + c);
    ushort4 hv;
    unsigned short* ha = (unsigned short*)&hv;
#pragma unroll
    for (int e = 0; e < 4; e++) ha[e] = f2bf(H[e]);
    *(ushort4*)&HT[(base * 64 + p) * 128 + n0] = hv;
    ushort4 s4 = *(const ushort4*)&ST[(base << 13) + p * 128 + n0];
    float dec = __expf(cums[bh * LSEQ + c * 64 + 63]);
    H[0] = H[0] * dec + bf2f(s4.x);
    H[1] = H[1] * dec + bf2f(s4.y);
    H[2] = H[2] * dec + bf2f(s4.z);
    H[3] = H[3] * dec + bf2f(s4.w);
  }
}

// ---------------- chunk phase C2: all heads + gate + RMSNorm fused ----------------
__global__ __launch_bounds__(256) void k_chunkC2(const unsigned short* __restrict__ bc,
                                                 const unsigned short* __restrict__ xs,
                                                 const unsigned short* __restrict__ zbuf,
                                                 const unsigned short* __restrict__ HT,
                                                 const float* __restrict__ cums,
                                                 const float* __restrict__ Dp,
                                                 const float* __restrict__ norm_w,
                                                 const unsigned short* __restrict__ yb,
                                                 unsigned short* __restrict__ zcat) {
  __shared__ __align__(16) unsigned short Hs[64 * 128];      // 16 KB
  __shared__ __align__(16) unsigned short yst[64 * 264];     // 33.8 KB (row stride 264)
  __shared__ float nw[256];
  int bid = blockIdx.x;
  int b = bid >> 6, c = bid & 63;
  int m0 = b * LSEQ + c * 64;
  int tid = threadIdx.x, w = tid >> 6, lane = tid & 63;
  if (tid < 256) nw[tid] = norm_w[tid];

  int rt = w * 16 + (lane & 15);
  const unsigned short* arow = bc + (size_t)(m0 + rt) * 256 + 128;
  bf16x8 af[4];
#pragma unroll
  for (int ks = 0; ks < 4; ks++)
    af[ks] = *(const bf16x8*)&arow[(ks * 4 + (lane >> 4)) * 8];

  for (int h = 0; h < 4; h++) {
    int bh = b * 4 + h;
    __syncthreads();
    for (int it = 0; it < 4; it++) {
      int idx = it * 256 + tid, row = idx >> 4, g = idx & 15;
      uint4 v = *(const uint4*)&HT[((size_t)(bh * 64 + c) * 64 + row) * 128 + g * 8];
      *(uint4*)((char*)Hs + row * 256 + ((g ^ (row & 7)) << 4)) = v;
    }
    float exq[4];
    {
      int tb = w * 16 + (lane >> 4) * 4;
#pragma unroll
      for (int j = 0; j < 4; j++) exq[j] = __expf(cums[bh * LSEQ + c * 64 + tb + j]);
    }
    __syncthreads();
    f32x4 acc[4];
#pragma unroll
    for (int i = 0; i < 4; i++) acc[i] = fz4();
#pragma unroll
    for (int ks = 0; ks < 4; ks++) {
      int g = ks * 4 + (lane >> 4);
#pragma unroll
      for (int ni = 0; ni < 4; ni++) {
        int rp = ni * 16 + (lane & 15);
        bf16x8 bfr = *(const bf16x8*)((char*)Hs + rp * 256 + ((g ^ (rp & 7)) << 4));
        acc[ni] = __builtin_amdgcn_mfma_f32_16x16x32_bf16(af[ks], bfr, acc[ni], 0, 0, 0);
      }
    }
#pragma unroll
    for (int ni = 0; ni < 4; ni++)
#pragma unroll
      for (int j = 0; j < 4; j++) {
        int t = w * 16 + (lane >> 4) * 4 + j;
        int p = ni * 16 + (lane & 15);
        yst[t * 264 + h * 64 + p] = f2bf(acc[ni][j] * exq[j]);
      }
  }
  __syncthreads();
  {
    int row = tid >> 2, hh = tid & 3;
    float Dh = Dp[hh];
    size_t moff = (size_t)(m0 + row) * 256 + hh * 64;
    const unsigned short* pyst = &yst[row * 264 + hh * 64];
    float gv[64];
    float ssum = 0.f;
#pragma unroll
    for (int q = 0; q < 8; q++) {
      uint4 vy = *(const uint4*)&yb[moff + q * 8];
      uint4 vx = *(const uint4*)&xs[moff + q * 8];
      uint4 vz = *(const uint4*)&zbuf[moff + q * 8];
      uint4 vi = *(const uint4*)&pyst[q * 8];
      const unsigned short* py = (const unsigned short*)&vy;
      const unsigned short* px = (const unsigned short*)&vx;
      const unsigned short* pz = (const unsigned short*)&vz;
      const unsigned short* pi = (const unsigned short*)&vi;
#pragma unroll
      for (int e = 0; e < 8; e++) {
        float yv = bf2f(py[e]) + bf2f(pi[e]) + Dh * bf2f(px[e]);
        float gg = yv * silu(bf2f(pz[e]));
        gv[q * 8 + e] = gg;
        ssum += gg * gg;
      }
    }
    ssum += __shfl_xor(ssum, 1, 64);
    ssum += __shfl_xor(ssum, 2, 64);
    float inv = rsqrtf(ssum * (1.f / 256.f) + 1e-5f);
#pragma unroll
    for (int q = 0; q < 8; q++) {
      uint4 vo;
      unsigned short* po = (unsigned short*)&vo;
#pragma unroll
      for (int e = 0; e < 8; e++)
        po[e] = f2bf(gv[q * 8 + e] * nw[hh * 64 + q * 8 + e] * inv);
      *(uint4*)&zcat[(size_t)(m0 + row) * 512 + 256 + hh * 64 + q * 8] = vo;
    }
  }
}

// ---------------- gate + RMSNorm (fallback only) ----------------
template <int MODE>
__global__ __launch_bounds__(256) void k_ycat(const unsigned short* __restrict__ y,
                                              const unsigned short* __restrict__ zsrc,
                                              const float* __restrict__ norm_w,
                                              unsigned short* __restrict__ ocat) {
  int bid = blockIdx.x;
  int tid = threadIdx.x, w = tid >> 6, lane = tid & 63;
  size_t m = (size_t)bid * 4 + w;
  int j0 = lane * 4;
  ushort4 yv = *(const ushort4*)&y[m * 256 + j0];
  ushort4 zv;
  if constexpr (MODE == 0) zv = *(const ushort4*)&zsrc[m * 256 + j0];
  else zv = *(const ushort4*)&zsrc[m * 1280 + 512 + j0];
  unsigned short ya[4] = {yv.x, yv.y, yv.z, yv.w};
  unsigned short za[4] = {zv.x, zv.y, zv.z, zv.w};
  float g[4]; float ssum = 0.f;
  for (int i = 0; i < 4; i++) {
    float gg = bf2f(ya[i]) * silu(bf2f(za[i]));
    g[i] = gg; ssum += gg * gg;
  }
  for (int off = 32; off; off >>= 1) ssum += __shfl_xor(ssum, off, 64);
  float inv = rsqrtf(ssum * (1.f / 256.f) + 1e-5f);
  ushort4 o2;
  unsigned short* o2a = (unsigned short*)&o2;
  for (int i = 0; i < 4; i++) o2a[i] = f2bf(g[i] * norm_w[j0 + i] * inv);
  *(ushort4*)&ocat[m * 512 + 256 + j0] = o2;
  if constexpr (MODE == 1) {
    ushort4 p0 = *(const ushort4*)&zsrc[m * 1280 + 2 * j0];
    ushort4 p1 = *(const ushort4*)&zsrc[m * 1280 + 2 * j0 + 4];
    ushort4 o1;
    unsigned short* o1a = (unsigned short*)&o1;
    o1a[0] = f2bf(silu(bf2f(p0.x)) * bf2f(p0.y));
    o1a[1] = f2bf(silu(bf2f(p0.z)) * bf2f(p0.w));
    o1a[2] = f2bf(silu(bf2f(p1.x)) * bf2f(p1.y));
    o1a[3] = f2bf(silu(bf2f(p1.z)) * bf2f(p1.w));
    *(ushort4*)&ocat[m * 512 + j0] = o1;
  }
}

// ---------------- SE FC ----------------
__global__ __launch_bounds__(512) void k_sefc(const float* __restrict__ smean,
                                              const float* __restrict__ w1, const float* __restrict__ b1,
                                              const float* __restrict__ w2, const float* __restrict__ b2,
                                              float* __restrict__ s2) {
  __shared__ float s1[512];
  int tid = threadIdx.x;
  int b = tid >> 6, j = tid & 63;
  float acc = b1[j];
  for (int k = 0; k < 256; k++) acc += smean[b * 256 + k] * (1.f / 4096.f) * w1[j * 256 + k];
  s1[b * 64 + j] = fmaxf(acc, 0.f);
  __syncthreads();
  for (int idx = tid; idx < 2048; idx += 512) {
    int bb = idx >> 8, c = idx & 255;
    float a2 = b2[c];
    for (int k = 0; k < 64; k++) a2 += s1[bb * 64 + k] * w2[c * 64 + k];
    s2[idx] = 1.f / (1.f + expf(-a2));
  }
}

// ---------------- final: elementwise SE scale on res_t ----------------
__global__ __launch_bounds__(256) void k_final(const unsigned short* __restrict__ rest,
                                               const float* __restrict__ s2,
                                               float* __restrict__ out) {
  int row = blockIdx.x;
  float s = s2[row];
  int tid = threadIdx.x;
  const unsigned short* p = rest + (size_t)row * 4096;
  float* o = out + (size_t)row * 4096;
  for (int it = 0; it < 2; it++) {
    int base = (it * 256 + tid) * 8;
    uint4 v = *(const uint4*)&p[base];
    const unsigned short* pv = (const unsigned short*)&v;
    float4 f0, f1;
    f0.x = bf2f(pv[0]) * s; f0.y = bf2f(pv[1]) * s;
    f0.z = bf2f(pv[2]) * s; f0.w = bf2f(pv[3]) * s;
    f1.x = bf2f(pv[4]) * s; f1.y = bf2f(pv[5]) * s;
    f1.z = bf2f(pv[6]) * s; f1.w = bf2f(pv[7]) * s;
    *(float4*)&o[base] = f0;
    *(float4*)&o[base + 4] = f1;
  }
}

// ---------------- launch ----------------
extern "C" void kernel_launch(void* const* d_in, const int* in_sizes, int n_in,
                              void* d_out, int out_size, void* d_ws, size_t ws_size,
                              hipStream_t stream) {
  const float* x         = (const float*)d_in[0];
  const float* in_proj_w = (const float*)d_in[1];
  const float* conv_w    = (const float*)d_in[2];
  const float* conv_b    = (const float*)d_in[3];
  const float* dt_bias   = (const float*)d_in[4];
  const float* A_log     = (const float*)d_in[5];
  const float* Dp        = (const float*)d_in[6];
  const float* norm_w    = (const float*)d_in[7];
  const float* out_projw = (const float*)d_in[8];
  const float* se_w1     = (const float*)d_in[9];
  const float* se_b1     = (const float*)d_in[10];
  const float* se_w2     = (const float*)d_in[11];
  const float* se_b2     = (const float*)d_in[12];
  float* out = (float*)d_out;
  char* ws = (char*)d_ws;

  const size_t NEED_CHUNKED = 220676096;

  if (ws_size >= NEED_CHUNKED) {
    unsigned short* ST16  = (unsigned short*)(ws + 0);          // chunkA->chunkB (33.5MB)
    unsigned short* ubf   = (unsigned short*)(ws + 0);          // pre-gemm1 tenant (16.7MB)
    unsigned short* res16 = (unsigned short*)(ws + 0);          // post-chunkB tenant (16.7MB)
    unsigned short* xbc   = (unsigned short*)(ws + 16777216);   // gemm1->conv tenant
    unsigned short* zcat  = (unsigned short*)(ws + 67108864);
    unsigned short* zbuf  = (unsigned short*)(ws + 100663296);
    unsigned short* xsb   = (unsigned short*)(ws + 117440512);
    unsigned short* bcb   = (unsigned short*)(ws + 134217728);
    unsigned short* HT    = (unsigned short*)(ws + 150994944);
    unsigned short* xsT   = (unsigned short*)(ws + 150994944);  // pre-chunkB tenant
    unsigned short* bT    = (unsigned short*)(ws + 167772160);  // pre-chunkB tenant
    unsigned short* ybuf  = (unsigned short*)(ws + 184549376);
    unsigned short* wpad  = (unsigned short*)(ws + 201326592);
    unsigned short* woutb = (unsigned short*)(ws + 202047488);
    float*          dtraw = (float*)(ws + 202309632);
    float*          dts   = (float*)(ws + 202833920);
    float*          cums  = (float*)(ws + 203358208);
    float*          smean = (float*)(ws + 203882496);
    float*          s2    = (float*)(ws + 203890688);

    k_prep<<<3968, 256, 0, stream>>>(in_proj_w, out_projw, wpad, woutb, x, ubf, smean);
    k_gemm<256, 256, 256, 2><<<256 * 11, 256, 0, stream>>>(ubf, wpad, (float*)xbc, zcat, zbuf, dtraw, 11);
    k_conv<<<1536, 256, 0, stream>>>(xbc, 512, conv_w, conv_b, xsb, bcb, xsT, bT,
                                     dtraw, dt_bias, A_log, dts, cums);
    k_chunkA<<<2048, 256, 0, stream>>>(bcb, xsT, bT, dts, cums, ST16, ybuf);
    k_chunkB<<<256, 256, 0, stream>>>(ST16, cums, HT);
    k_chunkC2<<<512, 256, 0, stream>>>(bcb, xsb, zbuf, HT, cums, Dp, norm_w, ybuf, zcat);
    k_gemm<512, 512, 512, 1><<<256 * 2, 256, 0, stream>>>(zcat, woutb, nullptr, res16, nullptr, smean, 2);
    k_sefc<<<1, 512, 0, stream>>>(smean, se_w1, se_b1, se_w2, se_b2, s2);
    k_final<<<2048, 256, 0, stream>>>(res16, s2, out);
  } else {
    unsigned short* ubf   = (unsigned short*)(ws + 0);
    unsigned short* res16 = (unsigned short*)(ws + 0);
    unsigned short* xsb   = (unsigned short*)(ws + 16777216);
    unsigned short* bcb   = (unsigned short*)(ws + 33554432);
    unsigned short* zx    = (unsigned short*)(ws + 50331648);
    float*          dtb   = (float*)(ws + 134217728);
    unsigned short* ybuf  = (unsigned short*)(ws + 134742016);
    unsigned short* ycat  = (unsigned short*)(ws + 151519232);
    unsigned short* wpad  = (unsigned short*)(ws + 185073664);
    unsigned short* woutb = (unsigned short*)(ws + 185794560);
    float*          smean = (float*)(ws + 186056704);
    float*          s2    = (float*)(ws + 186064896);

    k_prep<<<3968, 256, 0, stream>>>(in_proj_w, out_projw, wpad, woutb, x, ubf, smean);
    k_gemm<256, 256, 256, 0><<<256 * 11, 256, 0, stream>>>(ubf, wpad, nullptr, zx, nullptr, dtb, 11);
    k_conv<<<1024, 256, 0, stream>>>(zx + 768, 1280, conv_w, conv_b, xsb, bcb, nullptr, nullptr,
                                     nullptr, nullptr, nullptr, nullptr, nullptr);
    k_scan<<<512, 256, 0, stream>>>(xsb, bcb, dtb, dt_bias, A_log, Dp, ybuf);
    k_ycat<1><<<8192, 256, 0, stream>>>(ybuf, zx, norm_w, ycat);
    k_gemm<512, 512, 512, 1><<<256 * 2, 256, 0, stream>>>(ycat, woutb, nullptr, res16, nullptr, smean, 2);
    k_sefc<<<1, 512, 0, stream>>>(smean, se_w1, se_b1, se_w2, se_b2, s2);
    k_final<<<2048, 256, 0, stream>>>(res16, s2, out);
  }
}

// Round 12
// 216.149 us; speedup vs baseline: 15.4351x; 15.4351x over previous
//
#include <hip/hip_runtime.h>
#include <stdint.h>

// ---------------- types / helpers ----------------
typedef __attribute__((ext_vector_type(8))) short bf16x8;
typedef __attribute__((ext_vector_type(4))) float f32x4;

__device__ __forceinline__ float bf2f(unsigned short u) {
  unsigned int x = ((unsigned int)u) << 16;
  return __builtin_bit_cast(float, x);
}
__device__ __forceinline__ unsigned short f2bf(float f) {
  unsigned int x = __builtin_bit_cast(unsigned int, f);
  unsigned int r = x + 0x7FFFu + ((x >> 16) & 1u);
  return (unsigned short)(r >> 16);
}
__device__ __forceinline__ float silu(float v) { return v / (1.f + __expf(-v)); }
__device__ __forceinline__ f32x4 fz4() { f32x4 z; z[0]=0.f; z[1]=0.f; z[2]=0.f; z[3]=0.f; return z; }

#define LSEQ 4096
#define DMODEL 256
#define NIN 1284
#define NINP 1408   // padded to 11*128

// ---------------- prep: weight cast/pad/interleave + x transpose + smean zero ----------------
__global__ __launch_bounds__(256) void k_prep(const float* __restrict__ w_in,
                                              const float* __restrict__ w_out,
                                              unsigned short* __restrict__ wpad,
                                              unsigned short* __restrict__ woutbf,
                                              const float* __restrict__ x,
                                              unsigned short* __restrict__ ubf,
                                              float* __restrict__ smean) {
  int bid = blockIdx.x;
  int tid = threadIdx.x;
  if (bid < 1920) {
    if (bid < 8) smean[bid * 256 + tid] = 0.f;   // zero SE accumulator (gemm2 atomics)
    int idx = bid * 256 + tid;
    const int tot1 = NINP * DMODEL;           // 360448
    if (idx < tot1) {
      int n = idx / DMODEL, k = idx % DMODEL;
      int src = (n < 512) ? ((n & 1) ? 256 + (n >> 1) : (n >> 1)) : n;
      float v = (src < NIN) ? w_in[src * DMODEL + k] : 0.f;
      wpad[idx] = f2bf(v);
    } else {
      int j = idx - tot1;                      // 256*512 = 131072
      woutbf[j] = f2bf(w_out[j]);
    }
    return;
  }
  __shared__ float t[64][65];
  int r = (bid - 1920) & 255;
  int b = (bid - 1920) >> 8;
  int lt = r >> 2, kt = r & 3;
  int l0 = lt * 64, k0 = kt * 64;
  int j = tid & 63, i0 = tid >> 6;
  for (int rr = 0; rr < 16; rr++) {
    int ki = i0 + rr * 4;
    t[ki][j] = x[(size_t)(b * DMODEL + k0 + ki) * LSEQ + l0 + j];
  }
  __syncthreads();
  for (int rr = 0; rr < 16; rr++) {
    int li = i0 + rr * 4;
    ubf[(size_t)(b * LSEQ + l0 + li) * DMODEL + k0 + j] = f2bf(t[j][li]);
  }
}

// ---------------- bf16 MFMA GEMM, 128x128 tile, BK=32, 2-phase double-buffered ----------------
// Per step: issue STAGE(t+1) -> ds_read+MFMA(t) -> __syncthreads (full drain; race-safe).
// EPI=0 (fallback): combined zx[m][1280] (z0/x0 interleaved in cols 0..511) + dt
// EPI=1: res_t bf16 [b][c][l] via outBF; dtb = smean (fused SE column sums, atomic)
// EPI=2 (chunked): zc=silu(z0)*x0 -> zcat cols 0..255; z -> zbuf; xBC -> xbc; dt -> dtb
template <int KDIM, int LDA, int LDB, int EPI>
__global__ __launch_bounds__(256) void k_gemm(const unsigned short* __restrict__ A,
                                              const unsigned short* __restrict__ B,
                                              float* __restrict__ outF,
                                              unsigned short* __restrict__ outBF,
                                              unsigned short* __restrict__ outBF2,
                                              float* __restrict__ dtb, int tilesN) {
  // LDS: staging = 2 bufs x (A 4096 + B 4096) shorts = 32 KB; epilogue reuses [0,17408)
  __shared__ __align__(16) short lds[17408];     // 34816 B
  int nwg = gridDim.x;
  int orig = blockIdx.x;
  int wgid = (nwg & 7) ? orig : ((orig & 7) * (nwg >> 3) + (orig >> 3));
  int tn = wgid % tilesN, tm = wgid / tilesN;
  int m0 = tm * 128, n0 = tn * 128;
  int tid = threadIdx.x;
  int w = tid >> 6, lane = tid & 63;
  int wr = w >> 1, wc = w & 1;
  f32x4 acc[4][4];
  for (int i = 0; i < 4; i++)
    for (int j = 0; j < 4; j++) acc[i][j] = fz4();

  // stage one 128x32 A tile + 128x32 B tile into buffer buf (pre-swizzled source)
  auto stage = [&](int k0, int buf) {
#pragma unroll
    for (int i = 0; i < 2; i++) {
      int rowblk = w * 32 + i * 16;
      int row = rowblk + (lane >> 2);
      int kc = (((lane & 3) ^ (row & 3)) << 3);
      const unsigned short* ga = A + (size_t)(m0 + row) * LDA + k0 + kc;
      __builtin_amdgcn_global_load_lds((const __attribute__((address_space(1))) unsigned int*)ga,
                                       (__attribute__((address_space(3))) unsigned int*)&lds[buf * 8192 + rowblk * 32],
                                       16, 0, 0);
      const unsigned short* gb = B + (size_t)(n0 + row) * LDB + k0 + kc;
      __builtin_amdgcn_global_load_lds((const __attribute__((address_space(1))) unsigned int*)gb,
                                       (__attribute__((address_space(3))) unsigned int*)&lds[buf * 8192 + 4096 + rowblk * 32],
                                       16, 0, 0);
    }
  };

  stage(0, 0);
  __syncthreads();

  const int nsteps = KDIM / 32;
  for (int t = 0; t < nsteps; t++) {
    int cur = t & 1;
    if (t + 1 < nsteps) stage((t + 1) * 32, cur ^ 1);
    int gq = lane >> 4;                       // logical granule 0..3
    const char* Abase = (const char*)&lds[cur * 8192];
    const char* Bbase = (const char*)&lds[cur * 8192 + 4096];
    bf16x8 af[4], bfr[4];
#pragma unroll
    for (int mi = 0; mi < 4; mi++) {
      int rt = wr * 64 + mi * 16 + (lane & 15);
      af[mi] = *(const bf16x8*)(Abase + rt * 64 + ((gq ^ (rt & 3)) << 4));
    }
#pragma unroll
    for (int ni = 0; ni < 4; ni++) {
      int rs = wc * 64 + ni * 16 + (lane & 15);
      bfr[ni] = *(const bf16x8*)(Bbase + rs * 64 + ((gq ^ (rs & 3)) << 4));
    }
#pragma unroll
    for (int mi = 0; mi < 4; mi++)
#pragma unroll
      for (int ni = 0; ni < 4; ni++)
        acc[mi][ni] = __builtin_amdgcn_mfma_f32_16x16x32_bf16(af[mi], bfr[ni], acc[mi][ni], 0, 0, 0);
    __syncthreads();   // full vmcnt+lgkmcnt drain: race-safe buffer swap
  }

  int fq = lane >> 4, fr = lane & 15;
  if constexpr (EPI == 1) {
    // res_t bf16 [b][c][l]: stage transposed (c-major, stride 136), coalesced row stores
    short* Ctl = lds;
    for (int mi = 0; mi < 4; mi++)
      for (int ni = 0; ni < 4; ni++)
        for (int j = 0; j < 4; j++) {
          int r = wr * 64 + mi * 16 + fq * 4 + j;     // l within tile
          int cch = wc * 64 + ni * 16 + fr;           // c within tile
          Ctl[cch * 136 + r] = (short)f2bf(acc[mi][ni][j]);
        }
    __syncthreads();
    int b = m0 >> 12, l0 = m0 & 4095;
    for (int it = 0; it < 4; it++) {
      int row = it * 32 + (tid >> 3);
      int cc = (tid & 7) * 16;
      uint4 v0 = *(const uint4*)&Ctl[row * 136 + cc];
      uint4 v1 = *(const uint4*)&Ctl[row * 136 + cc + 8];
      unsigned short* dst = outBF + ((size_t)(b * 256 + n0 + row)) * 4096 + l0 + cc;
      *(uint4*)dst = v0;
      *(uint4*)&dst[8] = v1;
    }
    // fused SE-mean column partials: dtb == smean
    {
      int cch = tid >> 1, hf = tid & 1;
      const short* prow = &Ctl[cch * 136 + hf * 64];
      float s = 0.f;
      for (int q = 0; q < 8; q++) {
        uint4 v = *(const uint4*)&prow[q * 8];
        const unsigned short* pv = (const unsigned short*)&v;
#pragma unroll
        for (int e = 0; e < 8; e++) s += bf2f(pv[e]);
      }
      s += __shfl_xor(s, 1, 64);
      if (!hf) atomicAdd(&dtb[b * 256 + n0 + cch], s);
    }
  } else if constexpr (EPI == 2) {
    unsigned short* xbc = (unsigned short*)outF;
    if (n0 >= 1280) {
      if (wc == 0 && fr < 4) {
        for (int mi = 0; mi < 4; mi++)
          for (int j = 0; j < 4; j++) {
            int m = m0 + wr * 64 + mi * 16 + fq * 4 + j;
            dtb[m * 4 + fr] = acc[mi][0][j];
          }
      }
    } else if (n0 < 512) {
      // zc = silu(z0)*x0 : even fr holds z0, odd fr holds x0 (interleaved rows)
      short* Ct = lds;
      for (int mi = 0; mi < 4; mi++)
        for (int ni = 0; ni < 4; ni++)
          for (int j = 0; j < 4; j++) {
            float v = acc[mi][ni][j];
            float vp = __shfl_xor(v, 1, 64);
            if (!(fr & 1)) {
              float zc = silu(v) * vp;
              Ct[(wr * 64 + mi * 16 + fq * 4 + j) * 72 + wc * 32 + ni * 8 + (fr >> 1)] =
                  (short)f2bf(zc);
            }
          }
      __syncthreads();
      int r = tid >> 1, base = (tid & 1) * 32;
      for (int it = 0; it < 4; it++) {
        int cc = base + it * 8;
        uint4 v = *(const uint4*)&Ct[r * 72 + cc];
        *(uint4*)&outBF[(size_t)(m0 + r) * 512 + (n0 >> 1) + cc] = v;
      }
    } else {
      short* Ct = lds;
      for (int mi = 0; mi < 4; mi++)
        for (int ni = 0; ni < 4; ni++)
          for (int j = 0; j < 4; j++)
            Ct[(wr * 64 + mi * 16 + fq * 4 + j) * 136 + wc * 64 + ni * 16 + fr] =
                (short)f2bf(acc[mi][ni][j]);
      __syncthreads();
      int rr = tid >> 4, cc = (tid & 15) * 8;
      for (int it = 0; it < 8; it++) {
        int r = it * 16 + rr;
        uint4 v = *(const uint4*)&Ct[r * 136 + cc];
        if (n0 < 768) *(uint4*)&outBF2[(size_t)(m0 + r) * 256 + (n0 - 512) + cc] = v;
        else *(uint4*)&xbc[(size_t)(m0 + r) * 512 + (n0 - 768) + cc] = v;
      }
    }
  } else {  // EPI == 0 fallback
    bool dttile = (n0 >= 1280);
    if (dttile) {
      if (wc == 0 && fr < 4) {
        for (int mi = 0; mi < 4; mi++)
          for (int j = 0; j < 4; j++) {
            int m = m0 + wr * 64 + mi * 16 + fq * 4 + j;
            dtb[m * 4 + fr] = acc[mi][0][j];
          }
      }
    } else {
      short* Ct = lds;
      for (int mi = 0; mi < 4; mi++)
        for (int ni = 0; ni < 4; ni++)
          for (int j = 0; j < 4; j++)
            Ct[(wr * 64 + mi * 16 + fq * 4 + j) * 136 + wc * 64 + ni * 16 + fr] =
                (short)f2bf(acc[mi][ni][j]);
      __syncthreads();
      int rr = tid >> 4, cc = (tid & 15) * 8;
      for (int it = 0; it < 8; it++) {
        int r = it * 16 + rr;
        uint4 v = *(const uint4*)&Ct[r * 136 + cc];
        *(uint4*)&outBF[(size_t)(m0 + r) * 1280 + n0 + cc] = v;
      }
    }
  }
}

// ---------------- depthwise causal conv (4 taps) + SiLU; + dtpre tail blocks ----------------
__global__ __launch_bounds__(256) void k_conv(const unsigned short* __restrict__ src, int stride,
                                              const float* __restrict__ conv_w,
                                              const float* __restrict__ conv_b,
                                              unsigned short* __restrict__ xs,
                                              unsigned short* __restrict__ bc,
                                              unsigned short* __restrict__ xsT,
                                              unsigned short* __restrict__ bT,
                                              const float* __restrict__ dtraw,
                                              const float* __restrict__ dt_bias,
                                              const float* __restrict__ A_log,
                                              float* __restrict__ dts,
                                              float* __restrict__ cums) {
  __shared__ __align__(16) unsigned short xt[35 * 512];
  int bid = blockIdx.x;
  int tid = threadIdx.x;
  if (bid >= 1024) {
    int w4 = tid >> 6, lane = tid & 63;
    int gc = (bid - 1024) * 4 + w4;
    int bh = gc >> 6, cc = gc & 63;
    int b2 = bh >> 2, h2 = bh & 3;
    int t = cc * 64 + lane;
    float v = dtraw[(size_t)(b2 * LSEQ + t) * 4 + h2] + dt_bias[h2];
    float dt = (v > 20.f) ? v : log1pf(__expf(v));
    float Ah = -__expf(A_log[h2]);
    float s = dt * Ah;
    for (int off = 1; off < 64; off <<= 1) {
      float o = __shfl_up(s, off, 64);
      if (lane >= off) s += o;
    }
    dts[bh * LSEQ + t] = dt;
    cums[bh * LSEQ + t] = s;
    return;
  }
  int b = bid >> 7;
  int t0 = (bid & 127) * 32;
  for (int id = tid; id < 35 * 64; id += 256) {
    int r = id >> 6, ch = id & 63;
    int t = t0 - 3 + r;
    float4 v;
    if (t < 0) v = make_float4(0.f, 0.f, 0.f, 0.f);
    else v = *(const float4*)&src[(size_t)(b * LSEQ + t) * stride + ch * 8];
    *(float4*)&xt[r * 512 + ch * 8] = v;
  }
  __syncthreads();
  int c0 = tid, c1 = tid + 256;
  float w0[4], w1[4];
  for (int k = 0; k < 4; k++) { w0[k] = conv_w[c0 * 4 + k]; w1[k] = conv_w[c1 * 4 + k]; }
  float bb0 = conv_b[c0], bb1 = conv_b[c1];
  unsigned short xa0[32], xa1[32];
#pragma unroll
  for (int tl = 0; tl < 32; tl++) {
    float a0 = bb0, a1 = bb1;
    for (int k = 0; k < 4; k++) {
      a0 += bf2f(xt[(tl + k) * 512 + c0]) * w0[k];
      a1 += bf2f(xt[(tl + k) * 512 + c1]) * w1[k];
    }
    a0 = silu(a0); a1 = silu(a1);
    unsigned short u0 = f2bf(a0), u1 = f2bf(a1);
    xa0[tl] = u0; xa1[tl] = u1;
    size_t row = (size_t)(b * LSEQ + t0 + tl);
    xs[row * 256 + c0] = u0;
    bc[row * 256 + (c1 - 256)] = u1;
  }
  if (xsT) {
    const uint4* p0 = (const uint4*)xa0;
    for (int k = 0; k < 4; k++)
      *(uint4*)&xsT[((size_t)(b * 256 + c0)) * LSEQ + t0 + k * 8] = p0[k];
    if (c1 < 384) {
      const uint4* p1 = (const uint4*)xa1;
      for (int k = 0; k < 4; k++)
        *(uint4*)&bT[((size_t)(b * 128 + (c1 - 256))) * LSEQ + t0 + k * 8] = p1[k];
    }
  }
}

// ---------------- OLD sequential scan (ws fallback) ----------------
__global__ __launch_bounds__(256) void k_scan(const unsigned short* __restrict__ xs,
                                              const unsigned short* __restrict__ bc,
                                              const float* __restrict__ dtb,
                                              const float* __restrict__ dt_bias,
                                              const float* __restrict__ A_log,
                                              const float* __restrict__ Dp,
                                              unsigned short* __restrict__ y) {
  __shared__ __align__(16) unsigned short bcl[32 * 256];
  __shared__ float xsl[32][4];
  __shared__ float dtl[32], dal[32];
  int bid = blockIdx.x;
  int b = bid >> 6;
  int h = (bid >> 4) & 3;
  int pg = bid & 15;
  int tid = threadIdx.x, w = tid >> 6, lane = tid & 63;
  int p = pg * 4 + w;
  float Ah = -expf(A_log[h]);
  float Dh = Dp[h];
  float bias = dt_bias[h];
  float h0 = 0.f, h1 = 0.f;
  for (int t0 = 0; t0 < LSEQ; t0 += 32) {
    for (int id = tid; id < 32 * 32; id += 256) {
      int r = id >> 5, ch = id & 31;
      *(float4*)&bcl[r * 256 + ch * 8] =
          *(const float4*)&bc[(size_t)(b * LSEQ + t0 + r) * 256 + ch * 8];
    }
    if (tid < 128) {
      int r = tid >> 2, pp = tid & 3;
      xsl[r][pp] = bf2f(xs[(size_t)(b * LSEQ + t0 + r) * 256 + h * 64 + pg * 4 + pp]);
    } else if (tid < 160) {
      int r = tid - 128;
      float v = dtb[(size_t)(b * LSEQ + t0 + r) * 4 + h] + bias;
      float dt = (v > 20.f) ? v : log1pf(expf(v));
      dtl[r] = dt;
      dal[r] = expf(dt * Ah);
    }
    __syncthreads();
    for (int tl = 0; tl < 32; tl++) {
      float dtv = dtl[tl], dav = dal[tl], xv = xsl[tl][w];
      float bn  = bf2f(bcl[tl * 256 + lane]);
      float bn2 = bf2f(bcl[tl * 256 + 64 + lane]);
      float cn  = bf2f(bcl[tl * 256 + 128 + lane]);
      float cn2 = bf2f(bcl[tl * 256 + 192 + lane]);
      float coef = dtv * xv;
      h0 = h0 * dav + coef * bn;
      h1 = h1 * dav + coef * bn2;
      float part = h0 * cn + h1 * cn2;
      for (int off = 32; off; off >>= 1) part += __shfl_xor(part, off, 64);
      if (lane == 0)
        y[(size_t)(b * LSEQ + t0 + tl) * 256 + h * 64 + p] = f2bf(part + Dh * xv);
    }
    __syncthreads();
  }
}

// ---------------- chunk phase A ----------------
__global__ __launch_bounds__(256) void k_chunkA(const unsigned short* __restrict__ bc,
                                                const unsigned short* __restrict__ xsT,
                                                const unsigned short* __restrict__ bT,
                                                const float* __restrict__ dts,
                                                const float* __restrict__ cums,
                                                unsigned short* __restrict__ ST,
                                                unsigned short* __restrict__ yb) {
  __shared__ __align__(16) unsigned short sh[25088];
  unsigned short* Bsm = sh;
  unsigned short* BTs = sh + 8192;
  unsigned short* XT  = sh + 16384;
  unsigned short* Ms  = sh + 20480;
  __shared__ float dtl[64], cuml[64], scl[64];
  int bid = blockIdx.x;
  int bh = bid >> 6, c = bid & 63;
  int b = bh >> 2, h = bh & 3;
  int m0 = b * LSEQ + c * 64;
  int tid = threadIdx.x, w = tid >> 6, lane = tid & 63;

  if (tid < 64) {
    dtl[tid] = dts[bh * LSEQ + c * 64 + tid];
    cuml[tid] = cums[bh * LSEQ + c * 64 + tid];
  }
  __syncthreads();
  float cumQ = cuml[63];

  for (int it = 0; it < 4; it++) {
    int idx = it * 256 + tid, row = idx >> 4, g = idx & 15;
    uint4 v = *(const uint4*)&bc[(size_t)(m0 + row) * 256 + g * 8];
    *(uint4*)((char*)Bsm + row * 256 + ((g ^ (row & 7)) << 4)) = v;
  }
  for (int it = 0; it < 2; it++) {
    int idx = it * 256 + tid, row = idx >> 3, g = idx & 7;
    uint4 v = *(const uint4*)&xsT[((size_t)(b * 256 + h * 64 + row)) * LSEQ + c * 64 + g * 8];
    *(uint4*)((char*)XT + row * 128 + ((g ^ (row & 7)) << 4)) = v;
  }
  if (tid < 64) scl[tid] = dtl[tid] * __expf(cumQ - cuml[tid]);
  __syncthreads();
  for (int it = 0; it < 4; it++) {
    int idx = it * 256 + tid, row = idx >> 3, g = idx & 7;
    uint4 v = *(const uint4*)&bT[((size_t)(b * 128 + row)) * LSEQ + c * 64 + g * 8];
    const unsigned short* pv = (const unsigned short*)&v;
    uint4 o; unsigned short* po = (unsigned short*)&o;
#pragma unroll
    for (int e = 0; e < 8; e++) po[e] = f2bf(bf2f(pv[e]) * scl[g * 8 + e]);
    *(uint4*)((char*)BTs + row * 128 + ((g ^ (row & 7)) << 4)) = o;
  }

  int rt = w * 16 + (lane & 15);
  const unsigned short* arow = bc + (size_t)(m0 + rt) * 256 + 128;
  f32x4 acc1[4];
#pragma unroll
  for (int i = 0; i < 4; i++) acc1[i] = fz4();
#pragma unroll
  for (int ks = 0; ks < 4; ks++) {
    int g = ks * 4 + (lane >> 4);
    bf16x8 a = *(const bf16x8*)&arow[g * 8];
#pragma unroll
    for (int ni = 0; ni < 4; ni++) {
      int rs = ni * 16 + (lane & 15);
      bf16x8 bfr = *(const bf16x8*)((char*)Bsm + rs * 256 + ((g ^ (rs & 7)) << 4));
      acc1[ni] = __builtin_amdgcn_mfma_f32_16x16x32_bf16(a, bfr, acc1[ni], 0, 0, 0);
    }
  }
#pragma unroll
  for (int ni = 0; ni < 4; ni++)
#pragma unroll
    for (int j = 0; j < 4; j++) {
      int t = w * 16 + (lane >> 4) * 4 + j;
      int s = ni * 16 + (lane & 15);
      float v = 0.f;
      if (t >= s) v = acc1[ni][j] * __expf(cuml[t] - cuml[s]) * dtl[s];
      *(unsigned short*)((char*)Ms + t * 128 + (((s >> 3) ^ (t & 7)) << 4) + ((s & 7) << 1)) = f2bf(v);
    }
  __syncthreads();

  f32x4 acc2[4], acc3[8];
#pragma unroll
  for (int i = 0; i < 4; i++) acc2[i] = fz4();
#pragma unroll
  for (int i = 0; i < 8; i++) acc3[i] = fz4();
#pragma unroll
  for (int ks = 0; ks < 2; ks++) {
    int g = ks * 4 + (lane >> 4);
    bf16x8 xf[4];
#pragma unroll
    for (int ni = 0; ni < 4; ni++) {
      int rp = ni * 16 + (lane & 15);
      xf[ni] = *(const bf16x8*)((char*)XT + rp * 128 + ((g ^ (rp & 7)) << 4));
    }
    {
      bf16x8 a = *(const bf16x8*)((char*)Ms + rt * 128 + ((g ^ (rt & 7)) << 4));
#pragma unroll
      for (int ni = 0; ni < 4; ni++)
        acc2[ni] = __builtin_amdgcn_mfma_f32_16x16x32_bf16(a, xf[ni], acc2[ni], 0, 0, 0);
    }
    {
      bf16x8 a3 = xf[w];
#pragma unroll
      for (int ni = 0; ni < 8; ni++) {
        int rn = ni * 16 + (lane & 15);
        bf16x8 bfr = *(const bf16x8*)((char*)BTs + rn * 128 + ((g ^ (rn & 7)) << 4));
        acc3[ni] = __builtin_amdgcn_mfma_f32_16x16x32_bf16(a3, bfr, acc3[ni], 0, 0, 0);
      }
    }
  }
  __syncthreads();
  unsigned short* STst = sh;
#pragma unroll
  for (int ni = 0; ni < 4; ni++)
#pragma unroll
    for (int j = 0; j < 4; j++) {
      int t = w * 16 + (lane >> 4) * 4 + j;
      int p = ni * 16 + (lane & 15);
      Ms[t * 72 + p] = f2bf(acc2[ni][j]);
    }
#pragma unroll
  for (int ni = 0; ni < 8; ni++)
#pragma unroll
    for (int j = 0; j < 4; j++) {
      int p = w * 16 + (lane >> 4) * 4 + j;
      int n = ni * 16 + (lane & 15);
      STst[p * 136 + n] = f2bf(acc3[ni][j]);
    }
  __syncthreads();
  {
    int rr = tid >> 3, cc = (tid & 7) * 8;
    for (int it = 0; it < 2; it++) {
      int t = it * 32 + rr;
      uint4 v = *(const uint4*)&Ms[t * 72 + cc];
      *(uint4*)&yb[(size_t)(m0 + t) * 256 + h * 64 + cc] = v;
    }
  }
  {
    unsigned short* stp = ST + ((size_t)bid << 13);
    int rr = tid >> 2, cc = (tid & 3) * 32;
    for (int q = 0; q < 4; q++) {
      uint4 v = *(const uint4*)&STst[rr * 136 + cc + q * 8];
      *(uint4*)&stp[rr * 128 + cc + q * 8] = v;
    }
  }
}

// ---------------- chunk phase B: sequential state carry (ST bf16) ----------------
__global__ __launch_bounds__(256) void k_chunkB(const unsigned short* __restrict__ ST,
                                                const float* __restrict__ cums,
                                                unsigned short* __restrict__ HT) {
  int bid = blockIdx.x;
  int bh = bid >> 3, psl = bid & 7;
  int p = psl * 8 + (threadIdx.x >> 5);
  int n0 = (threadIdx.x & 31) * 4;
  float H[4] = {0.f, 0.f, 0.f, 0.f};
  for (int c = 0; c < 64; c++) {
    size_t base = (size_t)(bh * 64 + c);
    ushort4 hv;
    unsigned short* ha = (unsigned short*)&hv;
#pragma unroll
    for (int e = 0; e < 4; e++) ha[e] = f2bf(H[e]);
    *(ushort4*)&HT[(base * 64 + p) * 128 + n0] = hv;
    ushort4 s4 = *(const ushort4*)&ST[(base << 13) + p * 128 + n0];
    float dec = __expf(cums[bh * LSEQ + c * 64 + 63]);
    H[0] = H[0] * dec + bf2f(s4.x);
    H[1] = H[1] * dec + bf2f(s4.y);
    H[2] = H[2] * dec + bf2f(s4.z);
    H[3] = H[3] * dec + bf2f(s4.w);
  }
}

// ---------------- chunk phase C2: all heads + gate + RMSNorm fused ----------------
__global__ __launch_bounds__(256) void k_chunkC2(const unsigned short* __restrict__ bc,
                                                 const unsigned short* __restrict__ xs,
                                                 const unsigned short* __restrict__ zbuf,
                                                 const unsigned short* __restrict__ HT,
                                                 const float* __restrict__ cums,
                                                 const float* __restrict__ Dp,
                                                 const float* __restrict__ norm_w,
                                                 const unsigned short* __restrict__ yb,
                                                 unsigned short* __restrict__ zcat) {
  __shared__ __align__(16) unsigned short Hs[64 * 128];      // 16 KB
  __shared__ __align__(16) unsigned short yst[64 * 264];     // 33.8 KB (row stride 264)
  __shared__ float nw[256];
  int bid = blockIdx.x;
  int b = bid >> 6, c = bid & 63;
  int m0 = b * LSEQ + c * 64;
  int tid = threadIdx.x, w = tid >> 6, lane = tid & 63;
  if (tid < 256) nw[tid] = norm_w[tid];

  int rt = w * 16 + (lane & 15);
  const unsigned short* arow = bc + (size_t)(m0 + rt) * 256 + 128;
  bf16x8 af[4];
#pragma unroll
  for (int ks = 0; ks < 4; ks++)
    af[ks] = *(const bf16x8*)&arow[(ks * 4 + (lane >> 4)) * 8];

  for (int h = 0; h < 4; h++) {
    int bh = b * 4 + h;
    __syncthreads();
    for (int it = 0; it < 4; it++) {
      int idx = it * 256 + tid, row = idx >> 4, g = idx & 15;
      uint4 v = *(const uint4*)&HT[((size_t)(bh * 64 + c) * 64 + row) * 128 + g * 8];
      *(uint4*)((char*)Hs + row * 256 + ((g ^ (row & 7)) << 4)) = v;
    }
    float exq[4];
    {
      int tb = w * 16 + (lane >> 4) * 4;
#pragma unroll
      for (int j = 0; j < 4; j++) exq[j] = __expf(cums[bh * LSEQ + c * 64 + tb + j]);
    }
    __syncthreads();
    f32x4 acc[4];
#pragma unroll
    for (int i = 0; i < 4; i++) acc[i] = fz4();
#pragma unroll
    for (int ks = 0; ks < 4; ks++) {
      int g = ks * 4 + (lane >> 4);
#pragma unroll
      for (int ni = 0; ni < 4; ni++) {
        int rp = ni * 16 + (lane & 15);
        bf16x8 bfr = *(const bf16x8*)((char*)Hs + rp * 256 + ((g ^ (rp & 7)) << 4));
        acc[ni] = __builtin_amdgcn_mfma_f32_16x16x32_bf16(af[ks], bfr, acc[ni], 0, 0, 0);
      }
    }
#pragma unroll
    for (int ni = 0; ni < 4; ni++)
#pragma unroll
      for (int j = 0; j < 4; j++) {
        int t = w * 16 + (lane >> 4) * 4 + j;
        int p = ni * 16 + (lane & 15);
        yst[t * 264 + h * 64 + p] = f2bf(acc[ni][j] * exq[j]);
      }
  }
  __syncthreads();
  {
    int row = tid >> 2, hh = tid & 3;
    float Dh = Dp[hh];
    size_t moff = (size_t)(m0 + row) * 256 + hh * 64;
    const unsigned short* pyst = &yst[row * 264 + hh * 64];
    float gv[64];
    float ssum = 0.f;
#pragma unroll
    for (int q = 0; q < 8; q++) {
      uint4 vy = *(const uint4*)&yb[moff + q * 8];
      uint4 vx = *(const uint4*)&xs[moff + q * 8];
      uint4 vz = *(const uint4*)&zbuf[moff + q * 8];
      uint4 vi = *(const uint4*)&pyst[q * 8];
      const unsigned short* py = (const unsigned short*)&vy;
      const unsigned short* px = (const unsigned short*)&vx;
      const unsigned short* pz = (const unsigned short*)&vz;
      const unsigned short* pi = (const unsigned short*)&vi;
#pragma unroll
      for (int e = 0; e < 8; e++) {
        float yv = bf2f(py[e]) + bf2f(pi[e]) + Dh * bf2f(px[e]);
        float gg = yv * silu(bf2f(pz[e]));
        gv[q * 8 + e] = gg;
        ssum += gg * gg;
      }
    }
    ssum += __shfl_xor(ssum, 1, 64);
    ssum += __shfl_xor(ssum, 2, 64);
    float inv = rsqrtf(ssum * (1.f / 256.f) + 1e-5f);
#pragma unroll
    for (int q = 0; q < 8; q++) {
      uint4 vo;
      unsigned short* po = (unsigned short*)&vo;
#pragma unroll
      for (int e = 0; e < 8; e++)
        po[e] = f2bf(gv[q * 8 + e] * nw[hh * 64 + q * 8 + e] * inv);
      *(uint4*)&zcat[(size_t)(m0 + row) * 512 + 256 + hh * 64 + q * 8] = vo;
    }
  }
}

// ---------------- gate + RMSNorm (fallback only) ----------------
template <int MODE>
__global__ __launch_bounds__(256) void k_ycat(const unsigned short* __restrict__ y,
                                              const unsigned short* __restrict__ zsrc,
                                              const float* __restrict__ norm_w,
                                              unsigned short* __restrict__ ocat) {
  int bid = blockIdx.x;
  int tid = threadIdx.x, w = tid >> 6, lane = tid & 63;
  size_t m = (size_t)bid * 4 + w;
  int j0 = lane * 4;
  ushort4 yv = *(const ushort4*)&y[m * 256 + j0];
  ushort4 zv;
  if constexpr (MODE == 0) zv = *(const ushort4*)&zsrc[m * 256 + j0];
  else zv = *(const ushort4*)&zsrc[m * 1280 + 512 + j0];
  unsigned short ya[4] = {yv.x, yv.y, yv.z, yv.w};
  unsigned short za[4] = {zv.x, zv.y, zv.z, zv.w};
  float g[4]; float ssum = 0.f;
  for (int i = 0; i < 4; i++) {
    float gg = bf2f(ya[i]) * silu(bf2f(za[i]));
    g[i] = gg; ssum += gg * gg;
  }
  for (int off = 32; off; off >>= 1) ssum += __shfl_xor(ssum, off, 64);
  float inv = rsqrtf(ssum * (1.f / 256.f) + 1e-5f);
  ushort4 o2;
  unsigned short* o2a = (unsigned short*)&o2;
  for (int i = 0; i < 4; i++) o2a[i] = f2bf(g[i] * norm_w[j0 + i] * inv);
  *(ushort4*)&ocat[m * 512 + 256 + j0] = o2;
  if constexpr (MODE == 1) {
    ushort4 p0 = *(const ushort4*)&zsrc[m * 1280 + 2 * j0];
    ushort4 p1 = *(const ushort4*)&zsrc[m * 1280 + 2 * j0 + 4];
    ushort4 o1;
    unsigned short* o1a = (unsigned short*)&o1;
    o1a[0] = f2bf(silu(bf2f(p0.x)) * bf2f(p0.y));
    o1a[1] = f2bf(silu(bf2f(p0.z)) * bf2f(p0.w));
    o1a[2] = f2bf(silu(bf2f(p1.x)) * bf2f(p1.y));
    o1a[3] = f2bf(silu(bf2f(p1.z)) * bf2f(p1.w));
    *(ushort4*)&ocat[m * 512 + j0] = o1;
  }
}

// ---------------- SE FC ----------------
__global__ __launch_bounds__(512) void k_sefc(const float* __restrict__ smean,
                                              const float* __restrict__ w1, const float* __restrict__ b1,
                                              const float* __restrict__ w2, const float* __restrict__ b2,
                                              float* __restrict__ s2) {
  __shared__ float s1[512];
  int tid = threadIdx.x;
  int b = tid >> 6, j = tid & 63;
  float acc = b1[j];
  for (int k = 0; k < 256; k++) acc += smean[b * 256 + k] * (1.f / 4096.f) * w1[j * 256 + k];
  s1[b * 64 + j] = fmaxf(acc, 0.f);
  __syncthreads();
  for (int idx = tid; idx < 2048; idx += 512) {
    int bb = idx >> 8, c = idx & 255;
    float a2 = b2[c];
    for (int k = 0; k < 64; k++) a2 += s1[bb * 64 + k] * w2[c * 64 + k];
    s2[idx] = 1.f / (1.f + expf(-a2));
  }
}

// ---------------- final: elementwise SE scale on res_t ----------------
__global__ __launch_bounds__(256) void k_final(const unsigned short* __restrict__ rest,
                                               const float* __restrict__ s2,
                                               float* __restrict__ out) {
  int row = blockIdx.x;
  float s = s2[row];
  int tid = threadIdx.x;
  const unsigned short* p = rest + (size_t)row * 4096;
  float* o = out + (size_t)row * 4096;
  for (int it = 0; it < 2; it++) {
    int base = (it * 256 + tid) * 8;
    uint4 v = *(const uint4*)&p[base];
    const unsigned short* pv = (const unsigned short*)&v;
    float4 f0, f1;
    f0.x = bf2f(pv[0]) * s; f0.y = bf2f(pv[1]) * s;
    f0.z = bf2f(pv[2]) * s; f0.w = bf2f(pv[3]) * s;
    f1.x = bf2f(pv[4]) * s; f1.y = bf2f(pv[5]) * s;
    f1.z = bf2f(pv[6]) * s; f1.w = bf2f(pv[7]) * s;
    *(float4*)&o[base] = f0;
    *(float4*)&o[base + 4] = f1;
  }
}

// ---------------- launch ----------------
extern "C" void kernel_launch(void* const* d_in, const int* in_sizes, int n_in,
                              void* d_out, int out_size, void* d_ws, size_t ws_size,
                              hipStream_t stream) {
  const float* x         = (const float*)d_in[0];
  const float* in_proj_w = (const float*)d_in[1];
  const float* conv_w    = (const float*)d_in[2];
  const float* conv_b    = (const float*)d_in[3];
  const float* dt_bias   = (const float*)d_in[4];
  const float* A_log     = (const float*)d_in[5];
  const float* Dp        = (const float*)d_in[6];
  const float* norm_w    = (const float*)d_in[7];
  const float* out_projw = (const float*)d_in[8];
  const float* se_w1     = (const float*)d_in[9];
  const float* se_b1     = (const float*)d_in[10];
  const float* se_w2     = (const float*)d_in[11];
  const float* se_b2     = (const float*)d_in[12];
  float* out = (float*)d_out;
  char* ws = (char*)d_ws;

  const size_t NEED_CHUNKED = 220676096;

  if (ws_size >= NEED_CHUNKED) {
    unsigned short* ST16  = (unsigned short*)(ws + 0);          // chunkA->chunkB (33.5MB)
    unsigned short* ubf   = (unsigned short*)(ws + 0);          // pre-gemm1 tenant (16.7MB)
    unsigned short* res16 = (unsigned short*)(ws + 0);          // post-chunkB tenant (16.7MB)
    unsigned short* xbc   = (unsigned short*)(ws + 16777216);   // gemm1->conv tenant
    unsigned short* zcat  = (unsigned short*)(ws + 67108864);
    unsigned short* zbuf  = (unsigned short*)(ws + 100663296);
    unsigned short* xsb   = (unsigned short*)(ws + 117440512);
    unsigned short* bcb   = (unsigned short*)(ws + 134217728);
    unsigned short* HT    = (unsigned short*)(ws + 150994944);
    unsigned short* xsT   = (unsigned short*)(ws + 150994944);  // pre-chunkB tenant
    unsigned short* bT    = (unsigned short*)(ws + 167772160);  // pre-chunkB tenant
    unsigned short* ybuf  = (unsigned short*)(ws + 184549376);
    unsigned short* wpad  = (unsigned short*)(ws + 201326592);
    unsigned short* woutb = (unsigned short*)(ws + 202047488);
    float*          dtraw = (float*)(ws + 202309632);
    float*          dts   = (float*)(ws + 202833920);
    float*          cums  = (float*)(ws + 203358208);
    float*          smean = (float*)(ws + 203882496);
    float*          s2    = (float*)(ws + 203890688);

    k_prep<<<3968, 256, 0, stream>>>(in_proj_w, out_projw, wpad, woutb, x, ubf, smean);
    k_gemm<256, 256, 256, 2><<<256 * 11, 256, 0, stream>>>(ubf, wpad, (float*)xbc, zcat, zbuf, dtraw, 11);
    k_conv<<<1536, 256, 0, stream>>>(xbc, 512, conv_w, conv_b, xsb, bcb, xsT, bT,
                                     dtraw, dt_bias, A_log, dts, cums);
    k_chunkA<<<2048, 256, 0, stream>>>(bcb, xsT, bT, dts, cums, ST16, ybuf);
    k_chunkB<<<256, 256, 0, stream>>>(ST16, cums, HT);
    k_chunkC2<<<512, 256, 0, stream>>>(bcb, xsb, zbuf, HT, cums, Dp, norm_w, ybuf, zcat);
    k_gemm<512, 512, 512, 1><<<256 * 2, 256, 0, stream>>>(zcat, woutb, nullptr, res16, nullptr, smean, 2);
    k_sefc<<<1, 512, 0, stream>>>(smean, se_w1, se_b1, se_w2, se_b2, s2);
    k_final<<<2048, 256, 0, stream>>>(res16, s2, out);
  } else {
    unsigned short* ubf   = (unsigned short*)(ws + 0);
    unsigned short* res16 = (unsigned short*)(ws + 0);
    unsigned short* xsb   = (unsigned short*)(ws + 16777216);
    unsigned short* bcb   = (unsigned short*)(ws + 33554432);
    unsigned short* zx    = (unsigned short*)(ws + 50331648);
    float*          dtb   = (float*)(ws + 134217728);
    unsigned short* ybuf  = (unsigned short*)(ws + 134742016);
    unsigned short* ycat  = (unsigned short*)(ws + 151519232);
    unsigned short* wpad  = (unsigned short*)(ws + 185073664);
    unsigned short* woutb = (unsigned short*)(ws + 185794560);
    float*          smean = (float*)(ws + 186056704);
    float*          s2    = (float*)(ws + 186064896);

    k_prep<<<3968, 256, 0, stream>>>(in_proj_w, out_projw, wpad, woutb, x, ubf, smean);
    k_gemm<256, 256, 256, 0><<<256 * 11, 256, 0, stream>>>(ubf, wpad, nullptr, zx, nullptr, dtb, 11);
    k_conv<<<1024, 256, 0, stream>>>(zx + 768, 1280, conv_w, conv_b, xsb, bcb, nullptr, nullptr,
                                     nullptr, nullptr, nullptr, nullptr, nullptr);
    k_scan<<<512, 256, 0, stream>>>(xsb, bcb, dtb, dt_bias, A_log, Dp, ybuf);
    k_ycat<1><<<8192, 256, 0, stream>>>(ybuf, zx, norm_w, ycat);
    k_gemm<512, 512, 512, 1><<<256 * 2, 256, 0, stream>>>(ycat, woutb, nullptr, res16, nullptr, smean, 2);
    k_sefc<<<1, 512, 0, stream>>>(smean, se_w1, se_b1, se_w2, se_b2, s2);
    k_final<<<2048, 256, 0, stream>>>(res16, s2, out);
  }
}